// Round 3
// baseline (145.341 us; speedup 1.0000x reference)
//
#include <hip/hip_runtime.h>
#include <hip/hip_cooperative_groups.h>
#include <math.h>

namespace cg = cooperative_groups;

#define D_DIM   1024
#define BS      80      // B * STEP
#define STEPS   5
#define ALPHA   0.01f
#define BN_EPS  1e-5f
#define L2_EPS  1e-12f

#define NBLK    256
#define NTHR    512

// ---------------------------------------------------------------------------
// One cooperative kernel, three phases separated by grid.sync():
//  P1: closed-form fast-weight readout q[n,:]  (one block per row, 80 busy)
//  P2: y = q @ W^T + b with fused BN column sums (wave-per-(4j x 10n) GEMV,
//      fully coalesced float4 loads, butterfly reduce, 8 atomics/wave)
//  P3: BN(stats) + ReLU + row L2-normalize       (one block per row)
// ---------------------------------------------------------------------------
__global__ __launch_bounds__(NTHR) void fused_all(
        const float* __restrict__ x,
        const float* __restrict__ W,
        const float* __restrict__ bvec,
        const float* __restrict__ gamma,
        const float* __restrict__ beta,
        float* __restrict__ out,
        float* __restrict__ q,
        float* __restrict__ y,
        float* __restrict__ colsum,     // colsumsq = colsum + 1024 (contiguous)
        float* __restrict__ colsumsq) {
    cg::grid_group grid = cg::this_grid();

    const int tid  = threadIdx.x;        // 0..511
    const int lane = tid & 63;
    const int wid  = tid >> 6;           // 0..7
    const int blk  = blockIdx.x;         // 0..255

    __shared__ float sh1[8][STEPS];
    __shared__ float sr[8];

    // ---- Phase 0: zero BN stat buffers (2048 contiguous floats) ----
    if (blk < 4) colsum[blk * NTHR + tid] = 0.f;

    // ---- Phase 1: q rows ----
    if (blk < BS) {
        const int n  = blk;
        const int t  = n >> 4;
        const int bb = n & 15;

        const float2 v = ((const float2*)(x + (size_t)n * D_DIM))[tid];

        float2 k[STEPS];
#pragma unroll
        for (int s = 0; s < STEPS; ++s)
            k[s] = ((const float2*)(x + (size_t)(bb * STEPS + s) * D_DIM))[tid];

        float p[STEPS];
#pragma unroll
        for (int s = 0; s < STEPS; ++s)
            p[s] = k[s].x * v.x + k[s].y * v.y;

#pragma unroll
        for (int off = 32; off; off >>= 1) {
#pragma unroll
            for (int s = 0; s < STEPS; ++s) p[s] += __shfl_xor(p[s], off, 64);
        }
        if (lane == 0) {
#pragma unroll
            for (int s = 0; s < STEPS; ++s) sh1[wid][s] = p[s];
        }
        __syncthreads();
        float c[STEPS];
#pragma unroll
        for (int s = 0; s < STEPS; ++s) {
            float acc = 0.f;
#pragma unroll
            for (int w = 0; w < 8; ++w) acc += sh1[w][s];
            c[s] = acc;
        }

        float2 acc = make_float2(0.f, 0.f);
        for (int s = 0; s <= t; ++s) {
            const float2 xs = k[s];
            acc.x = acc.x * (1.f - ALPHA * xs.x * xs.x) + c[s] * xs.x;
            acc.y = acc.y * (1.f - ALPHA * xs.y * xs.y) + c[s] * xs.y;
        }
        acc.x *= ALPHA; acc.y *= ALPHA;
        ((float2*)(q + (size_t)n * D_DIM))[tid] = acc;
    }

    grid.sync();

    // ---- Phase 2: GEMV y = q @ W^T + b, fused column sums ----
    {
        const int gwave = blk * 8 + wid;      // 0..2047
        const int jg    = gwave & 255;        // j-group: j0 = jg*4
        const int ng    = gwave >> 8;         // 0..7
        const int j0    = jg * 4;
        const int n0    = ng * 10;

        const float4* __restrict__ W4 = (const float4*)W;
        const float4* __restrict__ q4 = (const float4*)q;

        float4 w[4][4];
#pragma unroll
        for (int jj = 0; jj < 4; ++jj)
#pragma unroll
            for (int m = 0; m < 4; ++m)
                w[jj][m] = W4[(size_t)(j0 + jj) * 256 + lane + 64 * m];

        const float4 b4 = ((const float4*)bvec)[jg];

        float csum[4] = {0.f, 0.f, 0.f, 0.f};
        float csq [4] = {0.f, 0.f, 0.f, 0.f};

        for (int nn = 0; nn < 10; ++nn) {
            const int n = n0 + nn;
            float4 qv[4];
#pragma unroll
            for (int m = 0; m < 4; ++m)
                qv[m] = q4[(size_t)n * 256 + lane + 64 * m];

            float s[4] = {0.f, 0.f, 0.f, 0.f};
#pragma unroll
            for (int jj = 0; jj < 4; ++jj) {
#pragma unroll
                for (int m = 0; m < 4; ++m) {
                    s[jj] += w[jj][m].x * qv[m].x + w[jj][m].y * qv[m].y
                           + w[jj][m].z * qv[m].z + w[jj][m].w * qv[m].w;
                }
            }
#pragma unroll
            for (int off = 32; off; off >>= 1) {
#pragma unroll
                for (int jj = 0; jj < 4; ++jj) s[jj] += __shfl_xor(s[jj], off, 64);
            }
            if (lane == 0) {
                float4 yv = make_float4(s[0] + b4.x, s[1] + b4.y,
                                        s[2] + b4.z, s[3] + b4.w);
                ((float4*)y)[(size_t)n * 256 + jg] = yv;
                csum[0] += yv.x; csum[1] += yv.y; csum[2] += yv.z; csum[3] += yv.w;
                csq[0] += yv.x * yv.x; csq[1] += yv.y * yv.y;
                csq[2] += yv.z * yv.z; csq[3] += yv.w * yv.w;
            }
        }
        if (lane == 0) {
#pragma unroll
            for (int jj = 0; jj < 4; ++jj) {
                atomicAdd(&colsum  [j0 + jj], csum[jj]);
                atomicAdd(&colsumsq[j0 + jj], csq[jj]);
            }
        }
    }

    grid.sync();

    // ---- Phase 3: BN + ReLU + row L2-normalize ----
    if (blk < BS) {
        const int n = blk;
        const float inv_bs = 1.f / (float)BS;

        float o[2];
        float ss = 0.f;
#pragma unroll
        for (int m = 0; m < 2; ++m) {
            const int j = tid + NTHR * m;
            const float mu   = colsum[j] * inv_bs;
            const float var  = colsumsq[j] * inv_bs - mu * mu;
            const float istd = rsqrtf(var + BN_EPS);
            float v = (y[(size_t)n * D_DIM + j] - mu) * istd * gamma[j] + beta[j];
            v = fmaxf(v, 0.f);
            o[m] = v;
            ss += v * v;
        }

#pragma unroll
        for (int off = 32; off; off >>= 1) ss += __shfl_xor(ss, off, 64);
        if (lane == 0) sr[wid] = ss;
        __syncthreads();
        float stot = 0.f;
#pragma unroll
        for (int w = 0; w < 8; ++w) stot += sr[w];

        const float scale = 1.f / fmaxf(sqrtf(stot), L2_EPS);
#pragma unroll
        for (int m = 0; m < 2; ++m)
            out[(size_t)n * D_DIM + tid + NTHR * m] = o[m] * scale;
    }
}

extern "C" void kernel_launch(void* const* d_in, const int* in_sizes, int n_in,
                              void* d_out, int out_size, void* d_ws, size_t ws_size,
                              hipStream_t stream) {
    const float* x     = (const float*)d_in[0];
    const float* W     = (const float*)d_in[1];
    const float* bvec  = (const float*)d_in[2];
    const float* gamma = (const float*)d_in[3];
    const float* beta  = (const float*)d_in[4];

    float* q        = (float*)d_ws;            // 80*1024
    float* y        = q + BS * D_DIM;          // 80*1024
    float* colsum   = y + BS * D_DIM;          // 1024
    float* colsumsq = colsum + D_DIM;          // 1024  (contiguous after colsum)

    float* out = (float*)d_out;

    void* args[] = {(void*)&x, (void*)&W, (void*)&bvec, (void*)&gamma,
                    (void*)&beta, (void*)&out, (void*)&q, (void*)&y,
                    (void*)&colsum, (void*)&colsumsq};
    hipLaunchCooperativeKernel((const void*)fused_all, dim3(NBLK), dim3(NTHR),
                               args, 0, stream);
}

// Round 4
// 115.219 us; speedup vs baseline: 1.2614x; 1.2614x over previous
//
#include <hip/hip_runtime.h>
#include <math.h>

#define D_DIM   1024
#define BS      80      // B * STEP
#define STEPS   5
#define ALPHA   0.01f
#define BN_EPS  1e-5f
#define L2_EPS  1e-12f

// ---------------------------------------------------------------------------
// KA: fused q-computation (into LDS) + GEMV y = q @ W^T + b.
// Grid: 256 blocks x 512 threads. Block owns (j-slice of 32, n-group of 10):
//   jslice = blk & 31  -> j in [jslice*32, jslice*32+32)
//   ng     = blk >> 5  -> n in [ng*10, ng*10+10)
// Phase 1: the block's 8 waves compute the 10 q rows into LDS (each wave one
// full row: lane holds 16 elems; dot-products via 64-lane butterfly so every
// lane ends with c_s; then the 5-step decayed recurrence). 32x redundant
// across blocks sharing ng — cheap (L2-hot x).
// Phase 2: wave w owns 4 W rows (64 VGPRs, coalesced float4 loads), loops the
// 10 LDS q rows, butterfly-reduces 4 sums, lane 0 stores y as float4.
// ---------------------------------------------------------------------------
__global__ __launch_bounds__(512) void kA(const float* __restrict__ x,
                                          const float* __restrict__ W,
                                          const float* __restrict__ bvec,
                                          float* __restrict__ y) {
    __shared__ float4 qs[10 * 256];   // 10 rows x 1024 floats = 40 KB

    const int tid    = threadIdx.x;
    const int lane   = tid & 63;
    const int wid    = tid >> 6;          // 0..7
    const int blk    = blockIdx.x;
    const int jslice = blk & 31;
    const int ng     = blk >> 5;          // 0..7
    const int n0     = ng * 10;

    // ---- Phase 1: q rows n0..n0+9 into LDS ----
    for (int r = wid; r < 10; r += 8) {
        const int n  = n0 + r;
        const int t  = n >> 4;
        const int bb = n & 15;

        const float4* __restrict__ xv = (const float4*)(x + (size_t)n * D_DIM);
        float4 v[4];
#pragma unroll
        for (int m = 0; m < 4; ++m) v[m] = xv[lane + 64 * m];

        float4 k[STEPS][4];
#pragma unroll
        for (int s = 0; s < STEPS; ++s) {
            const float4* __restrict__ xk =
                (const float4*)(x + (size_t)(bb * STEPS + s) * D_DIM);
#pragma unroll
            for (int m = 0; m < 4; ++m) k[s][m] = xk[lane + 64 * m];
        }

        float p[STEPS];
#pragma unroll
        for (int s = 0; s < STEPS; ++s) {
            float acc = 0.f;
#pragma unroll
            for (int m = 0; m < 4; ++m) {
                acc += k[s][m].x * v[m].x + k[s][m].y * v[m].y
                     + k[s][m].z * v[m].z + k[s][m].w * v[m].w;
            }
            p[s] = acc;
        }
#pragma unroll
        for (int off = 32; off; off >>= 1) {
#pragma unroll
            for (int s = 0; s < STEPS; ++s) p[s] += __shfl_xor(p[s], off, 64);
        }
        // every lane now holds the full dot products c_s = p[s]

#pragma unroll
        for (int m = 0; m < 4; ++m) {
            float4 acc = make_float4(0.f, 0.f, 0.f, 0.f);
            for (int s = 0; s <= t; ++s) {
                const float4 xs = k[s][m];
                const float  cs = p[s];
                acc.x = acc.x * (1.f - ALPHA * xs.x * xs.x) + cs * xs.x;
                acc.y = acc.y * (1.f - ALPHA * xs.y * xs.y) + cs * xs.y;
                acc.z = acc.z * (1.f - ALPHA * xs.z * xs.z) + cs * xs.z;
                acc.w = acc.w * (1.f - ALPHA * xs.w * xs.w) + cs * xs.w;
            }
            acc.x *= ALPHA; acc.y *= ALPHA; acc.z *= ALPHA; acc.w *= ALPHA;
            qs[r * 256 + lane + 64 * m] = acc;
        }
    }
    __syncthreads();

    // ---- Phase 2: GEMV for this block's 32 columns x 10 rows ----
    const int j0 = jslice * 32 + wid * 4;

    const float4* __restrict__ W4 = (const float4*)W;
    float4 w[4][4];
#pragma unroll
    for (int jj = 0; jj < 4; ++jj)
#pragma unroll
        for (int m = 0; m < 4; ++m)
            w[jj][m] = W4[(size_t)(j0 + jj) * 256 + lane + 64 * m];

    const float4 b4 = ((const float4*)bvec)[j0 >> 2];

    for (int nn = 0; nn < 10; ++nn) {
        float4 qv[4];
#pragma unroll
        for (int m = 0; m < 4; ++m) qv[m] = qs[nn * 256 + lane + 64 * m];

        float s[4] = {0.f, 0.f, 0.f, 0.f};
#pragma unroll
        for (int jj = 0; jj < 4; ++jj) {
#pragma unroll
            for (int m = 0; m < 4; ++m) {
                s[jj] += w[jj][m].x * qv[m].x + w[jj][m].y * qv[m].y
                       + w[jj][m].z * qv[m].z + w[jj][m].w * qv[m].w;
            }
        }
#pragma unroll
        for (int off = 32; off; off >>= 1) {
#pragma unroll
            for (int jj = 0; jj < 4; ++jj) s[jj] += __shfl_xor(s[jj], off, 64);
        }
        if (lane == 0) {
            ((float4*)y)[(size_t)(n0 + nn) * 256 + (j0 >> 2)] =
                make_float4(s[0] + b4.x, s[1] + b4.y, s[2] + b4.z, s[3] + b4.w);
        }
    }
}

// ---------------------------------------------------------------------------
// KB: BN (column stats over the 80-row batch, recomputed redundantly per
// block from y — 320 KB L2-hot stream) + ReLU + row L2-normalize.
// Grid: 80 blocks x 256 threads; thread owns one float4 column group.
// ---------------------------------------------------------------------------
__global__ __launch_bounds__(256) void kB(const float* __restrict__ y,
                                          const float* __restrict__ gamma,
                                          const float* __restrict__ beta,
                                          float* __restrict__ out) {
    const int n   = blockIdx.x;
    const int tid = threadIdx.x;

    const float4* __restrict__ y4 = (const float4*)y;

    float4 sum  = make_float4(0.f, 0.f, 0.f, 0.f);
    float4 sq   = make_float4(0.f, 0.f, 0.f, 0.f);
    float4 mine = make_float4(0.f, 0.f, 0.f, 0.f);
#pragma unroll 8
    for (int r = 0; r < BS; ++r) {
        const float4 v = y4[(size_t)r * 256 + tid];
        if (r == n) mine = v;
        sum.x += v.x; sum.y += v.y; sum.z += v.z; sum.w += v.w;
        sq.x += v.x * v.x; sq.y += v.y * v.y;
        sq.z += v.z * v.z; sq.w += v.w * v.w;
    }

    const float inv_bs = 1.f / (float)BS;
    const float4 g4 = ((const float4*)gamma)[tid];
    const float4 be4 = ((const float4*)beta)[tid];

    float4 o;
    {
        const float mux = sum.x * inv_bs, muy = sum.y * inv_bs;
        const float muz = sum.z * inv_bs, muw = sum.w * inv_bs;
        const float ix = rsqrtf(sq.x * inv_bs - mux * mux + BN_EPS);
        const float iy = rsqrtf(sq.y * inv_bs - muy * muy + BN_EPS);
        const float iz = rsqrtf(sq.z * inv_bs - muz * muz + BN_EPS);
        const float iw = rsqrtf(sq.w * inv_bs - muw * muw + BN_EPS);
        o.x = fmaxf((mine.x - mux) * ix * g4.x + be4.x, 0.f);
        o.y = fmaxf((mine.y - muy) * iy * g4.y + be4.y, 0.f);
        o.z = fmaxf((mine.z - muz) * iz * g4.z + be4.z, 0.f);
        o.w = fmaxf((mine.w - muw) * iw * g4.w + be4.w, 0.f);
    }

    float ss = o.x * o.x + o.y * o.y + o.z * o.z + o.w * o.w;
#pragma unroll
    for (int off = 32; off; off >>= 1) ss += __shfl_xor(ss, off, 64);
    __shared__ float sred[4];
    if ((tid & 63) == 0) sred[tid >> 6] = ss;
    __syncthreads();
    const float stot = sred[0] + sred[1] + sred[2] + sred[3];

    const float scale = 1.f / fmaxf(sqrtf(stot), L2_EPS);
    o.x *= scale; o.y *= scale; o.z *= scale; o.w *= scale;
    ((float4*)out)[(size_t)n * 256 + tid] = o;
}

extern "C" void kernel_launch(void* const* d_in, const int* in_sizes, int n_in,
                              void* d_out, int out_size, void* d_ws, size_t ws_size,
                              hipStream_t stream) {
    const float* x     = (const float*)d_in[0];
    const float* W     = (const float*)d_in[1];
    const float* bvec  = (const float*)d_in[2];
    const float* gamma = (const float*)d_in[3];
    const float* beta  = (const float*)d_in[4];

    float* y   = (float*)d_ws;        // 80*1024 floats
    float* out = (float*)d_out;

    kA<<<256, 512, 0, stream>>>(x, W, bvec, y);
    kB<<<BS,  256, 0, stream>>>(y, gamma, beta, out);
}

// Round 5
// 104.207 us; speedup vs baseline: 1.3947x; 1.1057x over previous
//
#include <hip/hip_runtime.h>
#include <math.h>

#define D_DIM   1024
#define BS      80      // B * STEP
#define STEPS   5
#define ALPHA   0.01f
#define BN_EPS  1e-5f
#define L2_EPS  1e-12f

// ---------------------------------------------------------------------------
// KA: fused q-computation (into LDS) + GEMV y = q @ W^T + b.
// Grid: 256 blocks x 512 threads. Block owns (j-slice of 32, n-group of 10):
//   jslice = blk & 31  -> j in [jslice*32, jslice*32+32)
//   ng     = blk >> 5  -> n in [ng*10, ng*10+10)
//
// Phase 1 (register-light; the round-4 version spilled 80 VGPRs of keys to
// scratch -> 85 MB of HBM traffic): whole block processes ONE row at a time;
// each thread owns a float2 (2 elems), so the live key set is k[5] float2 =
// 10 VGPRs, kept across dot-product AND recurrence passes. Dots: per-thread
// partial -> 64-lane butterfly -> 8 wave partials in double-buffered LDS ->
// every thread sums them (broadcast reads). One __syncthreads per row.
//
// Phase 2: wave w owns 4 W rows (64 VGPRs, coalesced float4 loads), loops the
// 10 LDS q rows, butterfly-reduces 4 sums, lane 0 stores y as float4.
// ---------------------------------------------------------------------------
__global__ __launch_bounds__(512) void kA(const float* __restrict__ x,
                                          const float* __restrict__ W,
                                          const float* __restrict__ bvec,
                                          float* __restrict__ y) {
    __shared__ float qs[10 * D_DIM];        // 40 KB
    __shared__ float shp[2][8][STEPS];      // double-buffered wave partials

    const int tid    = threadIdx.x;          // 0..511
    const int lane   = tid & 63;
    const int wid    = tid >> 6;             // 0..7
    const int blk    = blockIdx.x;
    const int jslice = blk & 31;
    const int ng     = blk >> 5;             // 0..7
    const int n0     = ng * 10;

    // ---- Phase 1: q rows n0..n0+9 into LDS, one row per block-iteration ----
    for (int r = 0; r < 10; ++r) {
        const int n  = n0 + r;
        const int t  = n >> 4;               // uniform across block
        const int bb = n & 15;

        const float2 v = ((const float2*)(x + (size_t)n * D_DIM))[tid];

        float2 k[STEPS];
#pragma unroll
        for (int s = 0; s < STEPS; ++s)
            k[s] = ((const float2*)(x + (size_t)(bb * STEPS + s) * D_DIM))[tid];

        float p[STEPS];
#pragma unroll
        for (int s = 0; s < STEPS; ++s)
            p[s] = k[s].x * v.x + k[s].y * v.y;

#pragma unroll
        for (int off = 32; off; off >>= 1) {
#pragma unroll
            for (int s = 0; s < STEPS; ++s) p[s] += __shfl_xor(p[s], off, 64);
        }
        if (lane == 0) {
#pragma unroll
            for (int s = 0; s < STEPS; ++s) shp[r & 1][wid][s] = p[s];
        }
        __syncthreads();

        float c[STEPS];
#pragma unroll
        for (int s = 0; s < STEPS; ++s) {
            float acc = 0.f;
#pragma unroll
            for (int w = 0; w < 8; ++w) acc += shp[r & 1][w][s];
            c[s] = acc;
        }

        float2 acc = make_float2(0.f, 0.f);
        for (int s = 0; s <= t; ++s) {
            const float2 xs = k[s];
            acc.x = acc.x * (1.f - ALPHA * xs.x * xs.x) + c[s] * xs.x;
            acc.y = acc.y * (1.f - ALPHA * xs.y * xs.y) + c[s] * xs.y;
        }
        ((float2*)qs)[r * (D_DIM / 2) + tid] =
            make_float2(acc.x * ALPHA, acc.y * ALPHA);
    }
    __syncthreads();

    // ---- Phase 2: GEMV for this block's 32 columns x 10 rows ----
    const int j0 = jslice * 32 + wid * 4;

    const float4* __restrict__ W4 = (const float4*)W;
    float4 w[4][4];
#pragma unroll
    for (int jj = 0; jj < 4; ++jj)
#pragma unroll
        for (int m = 0; m < 4; ++m)
            w[jj][m] = W4[(size_t)(j0 + jj) * 256 + lane + 64 * m];

    const float4 b4 = ((const float4*)bvec)[j0 >> 2];
    const float4* qs4 = (const float4*)qs;

    for (int nn = 0; nn < 10; ++nn) {
        float4 qv[4];
#pragma unroll
        for (int m = 0; m < 4; ++m) qv[m] = qs4[nn * 256 + lane + 64 * m];

        float s[4] = {0.f, 0.f, 0.f, 0.f};
#pragma unroll
        for (int jj = 0; jj < 4; ++jj) {
#pragma unroll
            for (int m = 0; m < 4; ++m) {
                s[jj] += w[jj][m].x * qv[m].x + w[jj][m].y * qv[m].y
                       + w[jj][m].z * qv[m].z + w[jj][m].w * qv[m].w;
            }
        }
#pragma unroll
        for (int off = 32; off; off >>= 1) {
#pragma unroll
            for (int jj = 0; jj < 4; ++jj) s[jj] += __shfl_xor(s[jj], off, 64);
        }
        if (lane == 0) {
            ((float4*)y)[(size_t)(n0 + nn) * 256 + (j0 >> 2)] =
                make_float4(s[0] + b4.x, s[1] + b4.y, s[2] + b4.z, s[3] + b4.w);
        }
    }
}

// ---------------------------------------------------------------------------
// KB: BN (column stats over the 80-row batch, recomputed redundantly per
// block from y — 320 KB L2-hot stream) + ReLU + row L2-normalize.
// Grid: 80 blocks x 256 threads; thread owns one float4 column group.
// ---------------------------------------------------------------------------
__global__ __launch_bounds__(256) void kB(const float* __restrict__ y,
                                          const float* __restrict__ gamma,
                                          const float* __restrict__ beta,
                                          float* __restrict__ out) {
    const int n   = blockIdx.x;
    const int tid = threadIdx.x;

    const float4* __restrict__ y4 = (const float4*)y;

    float4 sum  = make_float4(0.f, 0.f, 0.f, 0.f);
    float4 sq   = make_float4(0.f, 0.f, 0.f, 0.f);
    float4 mine = make_float4(0.f, 0.f, 0.f, 0.f);
#pragma unroll 8
    for (int r = 0; r < BS; ++r) {
        const float4 v = y4[(size_t)r * 256 + tid];
        if (r == n) mine = v;
        sum.x += v.x; sum.y += v.y; sum.z += v.z; sum.w += v.w;
        sq.x += v.x * v.x; sq.y += v.y * v.y;
        sq.z += v.z * v.z; sq.w += v.w * v.w;
    }

    const float inv_bs = 1.f / (float)BS;
    const float4 g4  = ((const float4*)gamma)[tid];
    const float4 be4 = ((const float4*)beta)[tid];

    float4 o;
    {
        const float mux = sum.x * inv_bs, muy = sum.y * inv_bs;
        const float muz = sum.z * inv_bs, muw = sum.w * inv_bs;
        const float ix = rsqrtf(sq.x * inv_bs - mux * mux + BN_EPS);
        const float iy = rsqrtf(sq.y * inv_bs - muy * muy + BN_EPS);
        const float iz = rsqrtf(sq.z * inv_bs - muz * muz + BN_EPS);
        const float iw = rsqrtf(sq.w * inv_bs - muw * muw + BN_EPS);
        o.x = fmaxf((mine.x - mux) * ix * g4.x + be4.x, 0.f);
        o.y = fmaxf((mine.y - muy) * iy * g4.y + be4.y, 0.f);
        o.z = fmaxf((mine.z - muz) * iz * g4.z + be4.z, 0.f);
        o.w = fmaxf((mine.w - muw) * iw * g4.w + be4.w, 0.f);
    }

    float ss = o.x * o.x + o.y * o.y + o.z * o.z + o.w * o.w;
#pragma unroll
    for (int off = 32; off; off >>= 1) ss += __shfl_xor(ss, off, 64);
    __shared__ float sred[4];
    if ((tid & 63) == 0) sred[tid >> 6] = ss;
    __syncthreads();
    const float stot = sred[0] + sred[1] + sred[2] + sred[3];

    const float scale = 1.f / fmaxf(sqrtf(stot), L2_EPS);
    o.x *= scale; o.y *= scale; o.z *= scale; o.w *= scale;
    ((float4*)out)[(size_t)n * 256 + tid] = o;
}

extern "C" void kernel_launch(void* const* d_in, const int* in_sizes, int n_in,
                              void* d_out, int out_size, void* d_ws, size_t ws_size,
                              hipStream_t stream) {
    const float* x     = (const float*)d_in[0];
    const float* W     = (const float*)d_in[1];
    const float* bvec  = (const float*)d_in[2];
    const float* gamma = (const float*)d_in[3];
    const float* beta  = (const float*)d_in[4];

    float* y   = (float*)d_ws;        // 80*1024 floats
    float* out = (float*)d_out;

    kA<<<256, 512, 0, stream>>>(x, W, bvec, y);
    kB<<<BS,  256, 0, stream>>>(y, gamma, beta, out);
}

// Round 6
// 80.691 us; speedup vs baseline: 1.8012x; 1.2914x over previous
//
#include <hip/hip_runtime.h>
#include <math.h>

#define D_DIM   1024
#define BS      80      // B * STEP
#define STEPS   5
#define ALPHA   0.01f
#define BN_EPS  1e-5f
#define L2_EPS  1e-12f

// ---------------------------------------------------------------------------
// K1: closed-form fast-weight readout.
//   q[n,i] = ALPHA * sum_{s=0..t} c_s * key_s[i] * prod_{r=s+1..t}(1-ALPHA*key_r[i]^2)
// t = n>>4 (step), bb = n&15 (batch); keys x[bb*5+s], query v = x[n],
// c_s = dot(key_s, v).  80 blocks x 256 threads, one float4 per thread.
// Blocks 0..7 also zero the 2048-float BN stats buffer (colsum||colsumsq).
// ---------------------------------------------------------------------------
__global__ __launch_bounds__(256) void k1_q(const float* __restrict__ x,
                                            float* __restrict__ q,
                                            float* __restrict__ stats) {
    const int n    = blockIdx.x;
    const int tid  = threadIdx.x;
    const int lane = tid & 63;
    const int wid  = tid >> 6;
    const int t    = n >> 4;
    const int bb   = n & 15;

    if (n < 8) stats[n * 256 + tid] = 0.f;   // 8*256 = 2048 floats

    const float4 v = ((const float4*)(x + (size_t)n * D_DIM))[tid];

    float4 k[STEPS];
#pragma unroll
    for (int s = 0; s < STEPS; ++s)
        k[s] = ((const float4*)(x + (size_t)(bb * STEPS + s) * D_DIM))[tid];

    float p[STEPS];
#pragma unroll
    for (int s = 0; s < STEPS; ++s)
        p[s] = k[s].x * v.x + k[s].y * v.y + k[s].z * v.z + k[s].w * v.w;

#pragma unroll
    for (int off = 32; off; off >>= 1) {
#pragma unroll
        for (int s = 0; s < STEPS; ++s) p[s] += __shfl_xor(p[s], off, 64);
    }

    __shared__ float sh[4][STEPS];
    if (lane == 0) {
#pragma unroll
        for (int s = 0; s < STEPS; ++s) sh[wid][s] = p[s];
    }
    __syncthreads();
    float c[STEPS];
#pragma unroll
    for (int s = 0; s < STEPS; ++s)
        c[s] = sh[0][s] + sh[1][s] + sh[2][s] + sh[3][s];

    float4 acc = make_float4(0.f, 0.f, 0.f, 0.f);
    for (int s = 0; s <= t; ++s) {
        const float4 xs = k[s];
        acc.x = acc.x * (1.f - ALPHA * xs.x * xs.x) + c[s] * xs.x;
        acc.y = acc.y * (1.f - ALPHA * xs.y * xs.y) + c[s] * xs.y;
        acc.z = acc.z * (1.f - ALPHA * xs.z * xs.z) + c[s] * xs.z;
        acc.w = acc.w * (1.f - ALPHA * xs.w * xs.w) + c[s] * xs.w;
    }
    acc.x *= ALPHA; acc.y *= ALPHA; acc.z *= ALPHA; acc.w *= ALPHA;
    ((float4*)(q + (size_t)n * D_DIM))[tid] = acc;
}

// ---------------------------------------------------------------------------
// K2: y = q @ W^T + b with fused BN column sums (atomics).
// Wave per (4 consecutive j, 8 n): lanes index K -> all W/q loads coalesced
// float4 (1 KiB/instr). 4 W rows live in 64 VGPRs, each q load reused 4x.
// Butterfly reduce; lane 0 stores y float4 + accumulates column sums,
// 8 atomics per wave at the end. 640 blocks x 256 = 2560 waves = 10/CU.
// ---------------------------------------------------------------------------
__global__ __launch_bounds__(256) void k2_gemm(const float* __restrict__ q,
                                               const float* __restrict__ W,
                                               const float* __restrict__ bvec,
                                               float* __restrict__ y,
                                               float* __restrict__ colsum,
                                               float* __restrict__ colsumsq) {
    const int tid  = threadIdx.x;
    const int lane = tid & 63;
    const int wid  = tid >> 6;
    const int wave = blockIdx.x * 4 + wid;   // 0..2559
    const int jg   = wave & 255;             // j0 = jg*4
    const int ng   = wave >> 8;              // 0..9
    const int j0   = jg * 4;
    const int n0   = ng * 8;

    const float4* __restrict__ W4 = (const float4*)W;
    const float4* __restrict__ q4 = (const float4*)q;

    float4 w[4][4];
#pragma unroll
    for (int jj = 0; jj < 4; ++jj)
#pragma unroll
        for (int m = 0; m < 4; ++m)
            w[jj][m] = W4[(size_t)(j0 + jj) * 256 + lane + 64 * m];

    const float4 b4 = ((const float4*)bvec)[jg];

    float csum[4] = {0.f, 0.f, 0.f, 0.f};
    float csq [4] = {0.f, 0.f, 0.f, 0.f};

#pragma unroll 2
    for (int nn = 0; nn < 8; ++nn) {
        const int n = n0 + nn;
        float4 qv[4];
#pragma unroll
        for (int m = 0; m < 4; ++m)
            qv[m] = q4[(size_t)n * 256 + lane + 64 * m];

        float s[4] = {0.f, 0.f, 0.f, 0.f};
#pragma unroll
        for (int jj = 0; jj < 4; ++jj) {
#pragma unroll
            for (int m = 0; m < 4; ++m) {
                s[jj] += w[jj][m].x * qv[m].x + w[jj][m].y * qv[m].y
                       + w[jj][m].z * qv[m].z + w[jj][m].w * qv[m].w;
            }
        }
#pragma unroll
        for (int off = 32; off; off >>= 1) {
#pragma unroll
            for (int jj = 0; jj < 4; ++jj) s[jj] += __shfl_xor(s[jj], off, 64);
        }
        if (lane == 0) {
            float4 yv = make_float4(s[0] + b4.x, s[1] + b4.y,
                                    s[2] + b4.z, s[3] + b4.w);
            ((float4*)y)[(size_t)n * 256 + jg] = yv;
            csum[0] += yv.x; csum[1] += yv.y; csum[2] += yv.z; csum[3] += yv.w;
            csq[0] += yv.x * yv.x; csq[1] += yv.y * yv.y;
            csq[2] += yv.z * yv.z; csq[3] += yv.w * yv.w;
        }
    }
    if (lane == 0) {
#pragma unroll
        for (int jj = 0; jj < 4; ++jj) {
            atomicAdd(&colsum  [j0 + jj], csum[jj]);
            atomicAdd(&colsumsq[j0 + jj], csq[jj]);
        }
    }
}

// ---------------------------------------------------------------------------
// K4: BN (stats from colsum/colsumsq) + ReLU + row L2-normalize.
// 80 blocks x 256 threads; thread owns one float4 column group per m-step.
// ---------------------------------------------------------------------------
__global__ __launch_bounds__(256) void k4_norm(const float* __restrict__ y,
                                               const float* __restrict__ colsum,
                                               const float* __restrict__ colsumsq,
                                               const float* __restrict__ gamma,
                                               const float* __restrict__ beta,
                                               float* __restrict__ out) {
    const int n   = blockIdx.x;
    const int tid = threadIdx.x;

    const float inv_bs = 1.f / (float)BS;

    const float4 yv  = ((const float4*)y)[(size_t)n * 256 + tid];
    const float4 cs  = ((const float4*)colsum)[tid];
    const float4 cq  = ((const float4*)colsumsq)[tid];
    const float4 g4  = ((const float4*)gamma)[tid];
    const float4 be4 = ((const float4*)beta)[tid];

    float4 o;
    {
        const float mux = cs.x * inv_bs, muy = cs.y * inv_bs;
        const float muz = cs.z * inv_bs, muw = cs.w * inv_bs;
        const float ix = rsqrtf(cq.x * inv_bs - mux * mux + BN_EPS);
        const float iy = rsqrtf(cq.y * inv_bs - muy * muy + BN_EPS);
        const float iz = rsqrtf(cq.z * inv_bs - muz * muz + BN_EPS);
        const float iw = rsqrtf(cq.w * inv_bs - muw * muw + BN_EPS);
        o.x = fmaxf((yv.x - mux) * ix * g4.x + be4.x, 0.f);
        o.y = fmaxf((yv.y - muy) * iy * g4.y + be4.y, 0.f);
        o.z = fmaxf((yv.z - muz) * iz * g4.z + be4.z, 0.f);
        o.w = fmaxf((yv.w - muw) * iw * g4.w + be4.w, 0.f);
    }

    float ss = o.x * o.x + o.y * o.y + o.z * o.z + o.w * o.w;
#pragma unroll
    for (int off = 32; off; off >>= 1) ss += __shfl_xor(ss, off, 64);
    __shared__ float sred[4];
    if ((tid & 63) == 0) sred[tid >> 6] = ss;
    __syncthreads();
    const float stot = sred[0] + sred[1] + sred[2] + sred[3];

    const float scale = 1.f / fmaxf(sqrtf(stot), L2_EPS);
    o.x *= scale; o.y *= scale; o.z *= scale; o.w *= scale;
    ((float4*)out)[(size_t)n * 256 + tid] = o;
}

extern "C" void kernel_launch(void* const* d_in, const int* in_sizes, int n_in,
                              void* d_out, int out_size, void* d_ws, size_t ws_size,
                              hipStream_t stream) {
    const float* x     = (const float*)d_in[0];
    const float* W     = (const float*)d_in[1];
    const float* bvec  = (const float*)d_in[2];
    const float* gamma = (const float*)d_in[3];
    const float* beta  = (const float*)d_in[4];

    float* q        = (float*)d_ws;            // 80*1024
    float* y        = q + BS * D_DIM;          // 80*1024
    float* colsum   = y + BS * D_DIM;          // 1024
    float* colsumsq = colsum + D_DIM;          // 1024 (contiguous after colsum)

    float* out = (float*)d_out;

    k1_q   <<<BS,  256, 0, stream>>>(x, q, colsum /* stats base */);
    k2_gemm<<<640, 256, 0, stream>>>(q, W, bvec, y, colsum, colsumsq);
    k4_norm<<<BS,  256, 0, stream>>>(y, colsum, colsumsq, gamma, beta, out);
}